// Round 5
// baseline (936.166 us; speedup 1.0000x reference)
//
#include <hip/hip_runtime.h>
#include <cstdint>
#include <cstddef>

// GAT forward: query = ufea@W^T + b; S = leaky2((q@inter^T)/sqrt(D)) masked by adj;
// out = softmax(S) @ inter.   N=10000 users, M=12000 items, D=128.
// R12: occupancy 2 -> 3 blocks/CU (the one untested axis; scheduling changes were
// null in R8/R11, so latency hiding must come from MORE RESIDENT WAVES):
//   - K/V single-buffered again: LDS 16+16+18 = 50 KB  (3 blocks = 150 <= 160)
//   - adj ping-pong dropped (-64 VGPR): in-tile loads, compacted to two 16-bit
//     masks right after the staging barrier (av regs die before QK) -> peak ~155
//   - __launch_bounds__(256,3) to claim 3 blocks/CU (12 waves/CU, +50% TLP)
//   - edge-column check hoisted to a tile-uniform branch (only tile 187 guarded)

#define N_USERS 10000
#define N_ITEMS 12000
#define HD      128
#define QROWS   10112      // 632*16 padded user rows
#define NCHUNK  12
#define TILE    64
#define NTILES  188        // ceil(12000/64); tile 187 has 32 valid items (zero-padded)
#define UBLOCKS 79         // fused user-blocks of 128
#define QBLOCKS 632        // query blocks of 16 users

typedef __bf16 bf16x8 __attribute__((ext_vector_type(8)));
typedef __bf16 bf16x4 __attribute__((ext_vector_type(4)));
typedef float  f32x4  __attribute__((ext_vector_type(4)));
typedef int    i32x4  __attribute__((ext_vector_type(4)));

typedef const __attribute__((address_space(1))) unsigned int g_u32;
typedef __attribute__((address_space(3))) unsigned int l_u32;

// ---------------- prep: inter -> kvg fragment image  +  query = ufea@W^T + b ----------------
// kvg layout per tile t (32KB): 32 chunks x 512 halves.
//   chunk c<16  (K): c=nt*4+kk, element[lane= qd*16+n][e] = K[t*64 + 4n+nt][kk*32+qd*8+e]
//   chunk 16+cc (V): cc=dt*2+kc, element[lane][e]        = inter[t*64+kc*32+qd*8+e][dt*16+n]
// Invalid items (>=12000) zero-filled -> fused needs no row clamps for K/V.
__global__ __launch_bounds__(256) void prep_kernel(const float* __restrict__ inter,
                                                   const float* __restrict__ ufea,
                                                   const float* __restrict__ W,
                                                   const float* __restrict__ bias,
                                                   __bf16* __restrict__ kvg,
                                                   __bf16* __restrict__ qg) {
    __shared__ __bf16 Tl[128 * 72];   // [d][item_local], pitch 72 (16B-aligned rows)
    const int t = threadIdx.x;
    const int lane = t & 63, wave = t >> 6;
    const int n = lane & 15, qd = lane >> 4;

    if (blockIdx.x < NTILES) {
        // ---- cast path ----
        const int tile = blockIdx.x;
        const int i0 = tile * 64;
        for (int it = 0; it < 8; ++it) {
            int g   = it * 256 + t;
            int row = g >> 5;            // 0..63 item_local
            int d   = (g & 31) * 4;      // 0..124
            int item = i0 + row;
            if (item < N_ITEMS) {
                f32x4 v = *(const f32x4*)(inter + (size_t)item * HD + d);
                Tl[(d + 0) * 72 + row] = (__bf16)v.x;
                Tl[(d + 1) * 72 + row] = (__bf16)v.y;
                Tl[(d + 2) * 72 + row] = (__bf16)v.z;
                Tl[(d + 3) * 72 + row] = (__bf16)v.w;
            } else {
                Tl[(d + 0) * 72 + row] = (__bf16)0.f;
                Tl[(d + 1) * 72 + row] = (__bf16)0.f;
                Tl[(d + 2) * 72 + row] = (__bf16)0.f;
                Tl[(d + 3) * 72 + row] = (__bf16)0.f;
            }
        }
        __syncthreads();
        __bf16* tbase = kvg + (size_t)tile * (32 * 512);
        // K chunks: re-read inter rows from global (L2-hot), cast to bf16
        #pragma unroll
        for (int j = 0; j < 4; ++j) {
            const int c = wave * 4 + j;            // nt = wave, kk = j
            int row = i0 + 4 * n + wave;
            bf16x8 o;
            if (row < N_ITEMS) {
                const float* p = inter + (size_t)row * HD + j * 32 + qd * 8;
                f32x4 lo = *(const f32x4*)p, hi = *(const f32x4*)(p + 4);
                o[0]=(__bf16)lo.x; o[1]=(__bf16)lo.y; o[2]=(__bf16)lo.z; o[3]=(__bf16)lo.w;
                o[4]=(__bf16)hi.x; o[5]=(__bf16)hi.y; o[6]=(__bf16)hi.z; o[7]=(__bf16)hi.w;
            } else {
                #pragma unroll
                for (int e = 0; e < 8; ++e) o[e] = (__bf16)0.f;
            }
            *(bf16x8*)(tbase + (size_t)c * 512 + lane * 8) = o;
        }
        // V chunks: from the LDS transpose
        #pragma unroll
        for (int j = 0; j < 4; ++j) {
            const int cc = wave * 4 + j;           // dt = cc>>1, kc = cc&1
            const int dt = cc >> 1, kc = cc & 1;
            bf16x8 v = *(const bf16x8*)&Tl[(dt * 16 + n) * 72 + kc * 32 + qd * 8];
            *(bf16x8*)(tbase + (size_t)(16 + cc) * 512 + lane * 8) = v;
        }
    } else {
        // ---- query path: 16 users/block; waves split the 8 output nt-tiles ----
        const int user0 = (blockIdx.x - NTILES) * 16;
        int arow = user0 + n; if (arow > N_USERS - 1) arow = N_USERS - 1;

        bf16x8 af[4];
        #pragma unroll
        for (int kk = 0; kk < 4; ++kk) {
            const float* p = ufea + (size_t)arow * HD + kk * 32 + qd * 8;
            f32x4 lo = *(const f32x4*)p, hi = *(const f32x4*)(p + 4);
            bf16x8 a;
            a[0]=(__bf16)lo.x; a[1]=(__bf16)lo.y; a[2]=(__bf16)lo.z; a[3]=(__bf16)lo.w;
            a[4]=(__bf16)hi.x; a[5]=(__bf16)hi.y; a[6]=(__bf16)hi.z; a[7]=(__bf16)hi.w;
            af[kk] = a;
        }
        #pragma unroll
        for (int h = 0; h < 2; ++h) {
            const int nt = wave * 2 + h;
            f32x4 acc = {0.f, 0.f, 0.f, 0.f};
            #pragma unroll
            for (int kk = 0; kk < 4; ++kk) {
                const float* p = W + (size_t)(nt * 16 + n) * HD + kk * 32 + qd * 8;
                f32x4 lo = *(const f32x4*)p, hi = *(const f32x4*)(p + 4);
                bf16x8 b;
                b[0]=(__bf16)lo.x; b[1]=(__bf16)lo.y; b[2]=(__bf16)lo.z; b[3]=(__bf16)lo.w;
                b[4]=(__bf16)hi.x; b[5]=(__bf16)hi.y; b[6]=(__bf16)hi.z; b[7]=(__bf16)hi.w;
                acc = __builtin_amdgcn_mfma_f32_16x16x32_bf16(af[kk], b, acc, 0, 0, 0);
            }
            const float bv = bias[nt * 16 + n];
            #pragma unroll
            for (int r = 0; r < 4; ++r) {
                int row = user0 + qd * 4 + r;      // < QROWS always
                qg[(size_t)row * HD + nt * 16 + n] = (__bf16)(acc[r] + bv);
            }
        }
    }
}

// ---------------- fused: S = q@k^T, mask+leaky+exp, O += P@V, l += rowsum ----------------
// 3 blocks/CU. Per tile: raw barrier A -> stage K/V + load adj -> __syncthreads
// (drains everything; exposed latency is covered by the other 2 blocks' waves)
// -> compact adj to 2x16-bit masks -> QK -> mask+exp -> PV.
__global__ __launch_bounds__(256, 3) void fused_kernel(const __bf16* __restrict__ qg,
                                                       const __bf16* __restrict__ kvg,
                                                       const int* __restrict__ adj,
                                                       float* __restrict__ Opart,
                                                       float* __restrict__ lpart) {
    __shared__ __bf16 Kbuf[16 * 512];     // chunk c=(nt*4+kk): K[j0+4n+nt][kk*32+qd*8..]
    __shared__ __bf16 Vbuf[16 * 512];     // chunk c=(dt*2+kc): V_T[dt*16+n][j0+kc*32+qd*8..]
    __shared__ __bf16 Pl[4][32 * 72];     // per-wave P: [user 0..31][item 0..63], pitch 72
    const int lane = threadIdx.x & 63, wave = threadIdx.x >> 6;
    const int n = lane & 15, qd = lane >> 4;
    const int user0 = blockIdx.y * 128 + wave * 32;   // wave covers users user0..user0+31
    const int chunk = blockIdx.x;
    const int t0 = (chunk * NTILES) / NCHUNK;
    const int t1 = ((chunk + 1) * NTILES) / NCHUNK;
    const float SC = (float)(1.4426950408889634 * 0.08838834764831845); // log2(e)/sqrt(128)

    bf16x8 qf[2][4];
    #pragma unroll
    for (int g = 0; g < 2; ++g)
        #pragma unroll
        for (int kk = 0; kk < 4; ++kk)
            qf[g][kk] = *(const bf16x8*)(qg + (size_t)(user0 + g * 16 + n) * HD + kk * 32 + qd * 8);

    f32x4 Oacc[2][8];
    #pragma unroll
    for (int g = 0; g < 2; ++g)
        #pragma unroll
        for (int dt = 0; dt < 8; ++dt) Oacc[g][dt] = (f32x4){0.f, 0.f, 0.f, 0.f};
    float lacc[2][4] = {{0.f,0.f,0.f,0.f},{0.f,0.f,0.f,0.f}};

    int adjOff[2][4];   // element offsets (10000*12000 < 2^31)
    #pragma unroll
    for (int g = 0; g < 2; ++g)
        #pragma unroll
        for (int r = 0; r < 4; ++r) {
            int u = user0 + g * 16 + qd * 4 + r;
            if (u > N_USERS - 1) u = N_USERS - 1;
            adjOff[g][r] = u * N_ITEMS;
        }
    __bf16* pw = &Pl[wave][0];

    for (int T = t0; T < t1; ++T) {
        const int j0 = T * TILE;
        const __bf16* tb = kvg + (size_t)T * (32 * 512);

        // barrier A: all waves finished reading Kbuf/Vbuf of tile T-1
        __builtin_amdgcn_s_barrier();

        // stage K(T)+V(T): 8 contiguous 1KB bursts per wave
        #pragma unroll
        for (int j = 0; j < 4; ++j) {
            const int c = wave * 4 + j;
            __builtin_amdgcn_global_load_lds((g_u32*)(tb + (size_t)c * 512 + lane * 8),
                                             (l_u32*)(&Kbuf[c * 512]), 16, 0, 0);
        }
        #pragma unroll
        for (int j = 0; j < 4; ++j) {
            const int c = wave * 4 + j;
            __builtin_amdgcn_global_load_lds((g_u32*)(tb + (size_t)(16 + c) * 512 + lane * 8),
                                             (l_u32*)(&Vbuf[c * 512]), 16, 0, 0);
        }
        // adj(T): one i32x4 per (group,row) covering items j0+4n..4n+3
        i32x4 av[2][4];
        {
            int col4 = j0 + 4 * n;
            if (col4 > N_ITEMS - 4) col4 = N_ITEMS - 4;
            #pragma unroll
            for (int g = 0; g < 2; ++g)
                #pragma unroll
                for (int r = 0; r < 4; ++r)
                    av[g][r] = __builtin_nontemporal_load((const i32x4*)(adj + adjOff[g][r] + col4));
        }
        __syncthreads();   // barrier B: drains staging + adj (TLP from 3 blocks covers)

        // compact adj to two 16-bit masks (av regs die here, before QK)
        unsigned m0 = 0, m1 = 0;
        #pragma unroll
        for (int r = 0; r < 4; ++r)
            #pragma unroll
            for (int nt = 0; nt < 4; ++nt) {
                m0 |= (unsigned)(av[0][r][nt] & 1) << (r * 4 + nt);
                m1 |= (unsigned)(av[1][r][nt] & 1) << (r * 4 + nt);
            }

        // QK: 16 B-frag reads, each feeding MFMAs for both user groups (32 MFMAs)
        f32x4 S[2][4];
        #pragma unroll
        for (int g = 0; g < 2; ++g)
            #pragma unroll
            for (int nt = 0; nt < 4; ++nt) S[g][nt] = (f32x4){0.f, 0.f, 0.f, 0.f};
        #pragma unroll
        for (int nt = 0; nt < 4; ++nt) {
            #pragma unroll
            for (int kk = 0; kk < 4; ++kk) {
                bf16x8 b = *(const bf16x8*)(&Kbuf[(nt * 4 + kk) * 512 + lane * 8]);
                S[0][nt] = __builtin_amdgcn_mfma_f32_16x16x32_bf16(qf[0][kk], b, S[0][nt], 0, 0, 0);
                S[1][nt] = __builtin_amdgcn_mfma_f32_16x16x32_bf16(qf[1][kk], b, S[1][nt], 0, 0, 0);
            }
        }

        // mask + leaky2 + exp2 -> P quads. Column-validity check only on the edge
        // tile (tile 187): hoisted to a tile-uniform branch.
        auto mask_body = [&](bool EDGE) {
            #pragma unroll
            for (int g = 0; g < 2; ++g) {
                const unsigned mg = g ? m1 : m0;
                #pragma unroll
                for (int r = 0; r < 4; ++r) {
                    bf16x4 pk;
                    #pragma unroll
                    for (int nt = 0; nt < 4; ++nt) {
                        float s = S[g][nt][r] * SC;
                        s = fminf(s, s + s);            // leaky_relu(slope 2), pre-scaled
                        bool on = (mg >> (r * 4 + nt)) & 1;
                        if (EDGE) on = on && (j0 + 4 * n + nt < N_ITEMS);
                        float p = on ? __builtin_amdgcn_exp2f(s) : 0.f;
                        lacc[g][r] += p;
                        pk[nt] = (__bf16)p;
                    }
                    *(bf16x4*)(pw + (g * 16 + qd * 4 + r) * 72 + 4 * n) = pk;
                }
            }
        };
        if (j0 + TILE > N_ITEMS) mask_body(true); else mask_body(false);

        // PV: 16 B-frag reads, each feeding both groups (32 MFMAs)
        #pragma unroll
        for (int kc = 0; kc < 2; ++kc) {
            bf16x8 af0 = *(const bf16x8*)(pw + (0 * 16 + n) * 72 + kc * 32 + qd * 8);
            bf16x8 af1 = *(const bf16x8*)(pw + (1 * 16 + n) * 72 + kc * 32 + qd * 8);
            #pragma unroll
            for (int dt = 0; dt < 8; ++dt) {
                bf16x8 b = *(const bf16x8*)(&Vbuf[(dt * 2 + kc) * 512 + lane * 8]);
                Oacc[0][dt] = __builtin_amdgcn_mfma_f32_16x16x32_bf16(af0, b, Oacc[0][dt], 0, 0, 0);
                Oacc[1][dt] = __builtin_amdgcn_mfma_f32_16x16x32_bf16(af1, b, Oacc[1][dt], 0, 0, 0);
            }
        }
    }

    // reduce l across the 16 lanes of each quad (lanes jointly cover all items)
    #pragma unroll
    for (int g = 0; g < 2; ++g)
        #pragma unroll
        for (int r = 0; r < 4; ++r) {
            float v = lacc[g][r];
            v += __shfl_xor(v, 1);
            v += __shfl_xor(v, 2);
            v += __shfl_xor(v, 4);
            v += __shfl_xor(v, 8);
            lacc[g][r] = v;
        }
    const size_t cb = (size_t)chunk * QROWS;
    #pragma unroll
    for (int g = 0; g < 2; ++g)
        #pragma unroll
        for (int r = 0; r < 4; ++r) {
            const int user = user0 + g * 16 + qd * 4 + r;
            if (user < N_USERS) {
                #pragma unroll
                for (int dt = 0; dt < 8; ++dt)
                    Opart[(cb + user) * HD + dt * 16 + n] = Oacc[g][dt][r];
                if (n == 0) lpart[cb + user] = lacc[g][r];
            }
        }
}

// ---------------- combine partials: out = (sum_c O_c) / (sum_c l_c) ----------------
__global__ __launch_bounds__(256) void combine_kernel(const float* __restrict__ Opart,
                                                      const float* __restrict__ lpart,
                                                      float* __restrict__ out) {
    const int g = blockIdx.x * 256 + threadIdx.x;   // 323584 threads exactly
    const int base = g * 4;
    const int user = base >> 7;
    const int d = base & 127;
    f32x4 acc = {0.f, 0.f, 0.f, 0.f};
    float l = 0.f;
    #pragma unroll
    for (int c = 0; c < NCHUNK; ++c) {
        acc += *(const f32x4*)(Opart + ((size_t)c * QROWS + user) * HD + d);
        l += lpart[(size_t)c * QROWS + user];
    }
    if (user < N_USERS) {
        f32x4 res = acc / l;
        *(f32x4*)(out + (size_t)user * HD + d) = res;
    }
}

extern "C" void kernel_launch(void* const* d_in, const int* in_sizes, int n_in,
                              void* d_out, int out_size, void* d_ws, size_t ws_size,
                              hipStream_t stream) {
    const float* ufea = (const float*)d_in[0];
    const float* inter = (const float*)d_in[1];
    const int*   adj  = (const int*)d_in[2];
    const float* W    = (const float*)d_in[3];
    const float* bias = (const float*)d_in[4];
    float* out = (float*)d_out;

    char* ws = (char*)d_ws;
    // layout (bytes):
    //   kvg   : 188*32*512*2      = 6,160,384   (tile-chunk-major K/V fragment image)
    //   qg    : 10112*128*2       = 2,588,672
    //   Opart : 12*10112*128*4    = 62,128,128
    //   lpart : 12*10112*4        = 485,376          total ~71.4 MB
    __bf16* kvg  = (__bf16*)(ws);
    __bf16* qg   = (__bf16*)(ws + 6160384);
    float*  Opart = (float*)(ws + 8749056);
    float*  lpart = (float*)(ws + 70877184);

    prep_kernel<<<dim3(NTILES + QBLOCKS), dim3(256), 0, stream>>>(inter, ufea, W, bias, kvg, qg);
    fused_kernel<<<dim3(NCHUNK, UBLOCKS), dim3(256), 0, stream>>>(qg, kvg, adj, Opart, lpart);
    combine_kernel<<<dim3(1264), dim3(256), 0, stream>>>(Opart, lpart, out);
}

// Round 6
// 730.740 us; speedup vs baseline: 1.2811x; 1.2811x over previous
//
#include <hip/hip_runtime.h>
#include <cstdint>
#include <cstddef>

// GAT forward: query = ufea@W^T + b; S = leaky2((q@inter^T)/sqrt(D)) masked by adj;
// out = softmax(S) @ inter.   N=10000 users, M=12000 items, D=128.
// R13: adj bitmask compression (the adj stream was fused's dominant cost:
//   480 MB read at ~53% BW efficiency inside the MFMA loop = ~2.6-4.9us/tile).
//   - prep gains a streaming pass: adj(int32, 480MB) -> mask64[user][tile]
//     (15 MB; bit k of word = adj[u][T*64+k]>0). Dedicated coalesced reader
//     runs at ~85% BW and overlaps with cast/query in the same launch.
//   - fused reads 8 BROADCAST u64 per wave per tile (L2/L3-hit) instead of
//     8 KB of adj per wave; edge-column guard deleted (pad bits are 0).
//   - NCHUNK 12 -> 6: 474 blocks = one fully-resident round; Opart halves.
//   - fused = R10 pipelined structure (dbuf K, post-barrier V stage), plain
//     __syncthreads, __launch_bounds__(256,2)  (R12's (256,3) spilled: VGPR 84,
//     +200MB scratch -> reverted).

#define N_USERS 10000
#define N_ITEMS 12000
#define HD      128
#define QROWS   10112      // 632*16 padded user rows
#define NCHUNK  6
#define TILE    64
#define NTILES  188        // ceil(12000/64); tile 187 has 32 valid items (zero-padded)
#define UBLOCKS 79         // fused user-blocks of 128
#define QBLOCKS 632        // query blocks of 16 users
#define AMBLOCKS 1228      // adj-mask blocks in prep
#define NWORDS  (N_USERS * NTILES)   // 1,880,000 mask words

typedef __bf16 bf16x8 __attribute__((ext_vector_type(8)));
typedef __bf16 bf16x4 __attribute__((ext_vector_type(4)));
typedef float  f32x4  __attribute__((ext_vector_type(4)));
typedef int    i32x4  __attribute__((ext_vector_type(4)));
typedef unsigned long long u64;

typedef const __attribute__((address_space(1))) unsigned int g_u32;
typedef __attribute__((address_space(3))) unsigned int l_u32;

// ---------------- prep: inter -> kvg image  +  query  +  adj -> mask64 ----------------
// kvg layout per tile t (32KB): 32 chunks x 512 halves.
//   chunk c<16  (K): c=nt*4+kk, element[lane= qd*16+n][e] = K[t*64 + 4n+nt][kk*32+qd*8+e]
//   chunk 16+cc (V): cc=dt*2+kc, element[lane][e]        = inter[t*64+kc*32+qd*8+e][dt*16+n]
// Invalid items (>=12000) zero-filled -> fused needs no row clamps for K/V.
__global__ __launch_bounds__(256) void prep_kernel(const float* __restrict__ inter,
                                                   const float* __restrict__ ufea,
                                                   const float* __restrict__ W,
                                                   const float* __restrict__ bias,
                                                   const int* __restrict__ adj,
                                                   __bf16* __restrict__ kvg,
                                                   __bf16* __restrict__ qg,
                                                   u64* __restrict__ mask) {
    __shared__ __bf16 Tl[128 * 72];   // [d][item_local], pitch 72 (16B-aligned rows)
    const int t = threadIdx.x;
    const int lane = t & 63, wave = t >> 6;
    const int n = lane & 15, qd = lane >> 4;

    if (blockIdx.x < NTILES) {
        // ---- cast path ----
        const int tile = blockIdx.x;
        const int i0 = tile * 64;
        for (int it = 0; it < 8; ++it) {
            int g   = it * 256 + t;
            int row = g >> 5;            // 0..63 item_local
            int d   = (g & 31) * 4;      // 0..124
            int item = i0 + row;
            if (item < N_ITEMS) {
                f32x4 v = *(const f32x4*)(inter + (size_t)item * HD + d);
                Tl[(d + 0) * 72 + row] = (__bf16)v.x;
                Tl[(d + 1) * 72 + row] = (__bf16)v.y;
                Tl[(d + 2) * 72 + row] = (__bf16)v.z;
                Tl[(d + 3) * 72 + row] = (__bf16)v.w;
            } else {
                Tl[(d + 0) * 72 + row] = (__bf16)0.f;
                Tl[(d + 1) * 72 + row] = (__bf16)0.f;
                Tl[(d + 2) * 72 + row] = (__bf16)0.f;
                Tl[(d + 3) * 72 + row] = (__bf16)0.f;
            }
        }
        __syncthreads();
        __bf16* tbase = kvg + (size_t)tile * (32 * 512);
        // K chunks: re-read inter rows from global (L2-hot), cast to bf16
        #pragma unroll
        for (int j = 0; j < 4; ++j) {
            const int c = wave * 4 + j;            // nt = wave, kk = j
            int row = i0 + 4 * n + wave;
            bf16x8 o;
            if (row < N_ITEMS) {
                const float* p = inter + (size_t)row * HD + j * 32 + qd * 8;
                f32x4 lo = *(const f32x4*)p, hi = *(const f32x4*)(p + 4);
                o[0]=(__bf16)lo.x; o[1]=(__bf16)lo.y; o[2]=(__bf16)lo.z; o[3]=(__bf16)lo.w;
                o[4]=(__bf16)hi.x; o[5]=(__bf16)hi.y; o[6]=(__bf16)hi.z; o[7]=(__bf16)hi.w;
            } else {
                #pragma unroll
                for (int e = 0; e < 8; ++e) o[e] = (__bf16)0.f;
            }
            *(bf16x8*)(tbase + (size_t)c * 512 + lane * 8) = o;
        }
        // V chunks: from the LDS transpose
        #pragma unroll
        for (int j = 0; j < 4; ++j) {
            const int cc = wave * 4 + j;           // dt = cc>>1, kc = cc&1
            const int dt = cc >> 1, kc = cc & 1;
            bf16x8 v = *(const bf16x8*)&Tl[(dt * 16 + n) * 72 + kc * 32 + qd * 8];
            *(bf16x8*)(tbase + (size_t)(16 + cc) * 512 + lane * 8) = v;
        }
    } else if (blockIdx.x < NTILES + QBLOCKS) {
        // ---- query path: 16 users/block; waves split the 8 output nt-tiles ----
        const int user0 = (blockIdx.x - NTILES) * 16;
        int arow = user0 + n; if (arow > N_USERS - 1) arow = N_USERS - 1;

        bf16x8 af[4];
        #pragma unroll
        for (int kk = 0; kk < 4; ++kk) {
            const float* p = ufea + (size_t)arow * HD + kk * 32 + qd * 8;
            f32x4 lo = *(const f32x4*)p, hi = *(const f32x4*)(p + 4);
            bf16x8 a;
            a[0]=(__bf16)lo.x; a[1]=(__bf16)lo.y; a[2]=(__bf16)lo.z; a[3]=(__bf16)lo.w;
            a[4]=(__bf16)hi.x; a[5]=(__bf16)hi.y; a[6]=(__bf16)hi.z; a[7]=(__bf16)hi.w;
            af[kk] = a;
        }
        #pragma unroll
        for (int h = 0; h < 2; ++h) {
            const int nt = wave * 2 + h;
            f32x4 acc = {0.f, 0.f, 0.f, 0.f};
            #pragma unroll
            for (int kk = 0; kk < 4; ++kk) {
                const float* p = W + (size_t)(nt * 16 + n) * HD + kk * 32 + qd * 8;
                f32x4 lo = *(const f32x4*)p, hi = *(const f32x4*)(p + 4);
                bf16x8 b;
                b[0]=(__bf16)lo.x; b[1]=(__bf16)lo.y; b[2]=(__bf16)lo.z; b[3]=(__bf16)lo.w;
                b[4]=(__bf16)hi.x; b[5]=(__bf16)hi.y; b[6]=(__bf16)hi.z; b[7]=(__bf16)hi.w;
                acc = __builtin_amdgcn_mfma_f32_16x16x32_bf16(af[kk], b, acc, 0, 0, 0);
            }
            const float bv = bias[nt * 16 + n];
            #pragma unroll
            for (int r = 0; r < 4; ++r) {
                int row = user0 + qd * 4 + r;      // < QROWS always
                qg[(size_t)row * HD + nt * 16 + n] = (__bf16)(acc[r] + bv);
            }
        }
    } else {
        // ---- adj -> mask64 streaming pass ----
        // word w = u*188 + T: bit k = adj[u][T*64+k] > 0  (k = 4n+nt).
        // One 16-lane group builds one word per iter: lane n reads i32x4 at
        // item 4n (256B contiguous per group), packs a nibble, OR-shuffle.
        const int gid = (blockIdx.x - (NTILES + QBLOCKS)) * 16 + (t >> 4);
        for (int w = gid; w < NWORDS; w += AMBLOCKS * 16) {
            const int u = w / NTILES;                 // const-div -> magic mul
            const int T = w - u * NTILES;
            const int col4 = T * 64 + 4 * n;
            const int col4c = (col4 <= N_ITEMS - 4) ? col4 : (N_ITEMS - 16);
            i32x4 av = __builtin_nontemporal_load(
                (const i32x4*)(adj + (size_t)u * N_ITEMS + col4c));
            unsigned nib = 0;
            #pragma unroll
            for (int nt = 0; nt < 4; ++nt)
                if ((col4 + nt < N_ITEMS) && (av[nt] > 0)) nib |= 1u << nt;
            unsigned lo = (n < 8) ? (nib << (4 * n)) : 0u;
            unsigned hi = (n >= 8) ? (nib << (4 * (n - 8))) : 0u;
            #pragma unroll
            for (int m = 1; m < 16; m <<= 1) {
                lo |= __shfl_xor(lo, m);
                hi |= __shfl_xor(hi, m);
            }
            if (n == 0) mask[w] = ((u64)hi << 32) | lo;
        }
    }
}

// ---------------- fused: S = q@k^T, mask+leaky+exp, O += P@V, l += rowsum ----------------
// Pipelined 2-barrier loop (R10 structure). Kbuf double-buffered (stage T+1
// issued before QK(T)); Vbuf single (stage T+1 issued after barrier2). adj is
// 8 broadcast u64 mask loads per wave per tile (L2/L3-hit), no edge guard.
__global__ __launch_bounds__(256, 2) void fused_kernel(const __bf16* __restrict__ qg,
                                                       const __bf16* __restrict__ kvg,
                                                       const u64* __restrict__ mask,
                                                       float* __restrict__ Opart,
                                                       float* __restrict__ lpart) {
    __shared__ __bf16 Kbuf[2][16 * 512];  // double-buffered K fragment chunks
    __shared__ __bf16 Vbuf[16 * 512];     // single-buffered V fragment chunks
    __shared__ __bf16 Pl[4][32 * 72];     // per-wave P: [user 0..31][item 0..63], pitch 72
    const int lane = threadIdx.x & 63, wave = threadIdx.x >> 6;
    const int n = lane & 15, qd = lane >> 4;
    const int user0 = blockIdx.y * 128 + wave * 32;   // wave covers users user0..user0+31
    const int chunk = blockIdx.x;
    const int t0 = (chunk * NTILES) / NCHUNK;
    const int t1 = ((chunk + 1) * NTILES) / NCHUNK;
    const float SC = (float)(1.4426950408889634 * 0.08838834764831845); // log2(e)/sqrt(128)

    bf16x8 qf[2][4];
    #pragma unroll
    for (int g = 0; g < 2; ++g)
        #pragma unroll
        for (int kk = 0; kk < 4; ++kk)
            qf[g][kk] = *(const bf16x8*)(qg + (size_t)(user0 + g * 16 + n) * HD + kk * 32 + qd * 8);

    f32x4 Oacc[2][8];
    #pragma unroll
    for (int g = 0; g < 2; ++g)
        #pragma unroll
        for (int dt = 0; dt < 8; ++dt) Oacc[g][dt] = (f32x4){0.f, 0.f, 0.f, 0.f};
    float lacc[2][4] = {{0.f,0.f,0.f,0.f},{0.f,0.f,0.f,0.f}};

    int maskRow[2][4];   // word offsets u*188 (10000*188 < 2^31)
    #pragma unroll
    for (int g = 0; g < 2; ++g)
        #pragma unroll
        for (int r = 0; r < 4; ++r) {
            int u = user0 + g * 16 + qd * 4 + r;
            if (u > N_USERS - 1) u = N_USERS - 1;
            maskRow[g][r] = u * NTILES;
        }
    __bf16* pw = &Pl[wave][0];

    // ---- prologue: stage K(t0)->Kbuf[0], V(t0)->Vbuf ----
    {
        const __bf16* tb = kvg + (size_t)t0 * (32 * 512);
        #pragma unroll
        for (int j = 0; j < 4; ++j) {
            const int c = wave * 4 + j;
            __builtin_amdgcn_global_load_lds((g_u32*)(tb + (size_t)c * 512 + lane * 8),
                                             (l_u32*)(&Kbuf[0][c * 512]), 16, 0, 0);
        }
        #pragma unroll
        for (int j = 0; j < 4; ++j) {
            const int c = wave * 4 + j;
            __builtin_amdgcn_global_load_lds((g_u32*)(tb + (size_t)(16 + c) * 512 + lane * 8),
                                             (l_u32*)(&Vbuf[c * 512]), 16, 0, 0);
        }
    }
    __syncthreads();

    int cur = 0;
    for (int T = t0; T < t1; ++T) {
        const bool more = (T + 1 < t1);
        const __bf16* tbn = kvg + (size_t)(T + 1) * (32 * 512);

        // (1) issue K(T+1) -> Kbuf[cur^1]  (flies under QK+mask, drained at barrier1)
        if (more) {
            #pragma unroll
            for (int j = 0; j < 4; ++j) {
                const int c = wave * 4 + j;
                __builtin_amdgcn_global_load_lds((g_u32*)(tbn + (size_t)c * 512 + lane * 8),
                                                 (l_u32*)(&Kbuf[cur ^ 1][c * 512]), 16, 0, 0);
            }
        }
        // (2) load the 8 broadcast mask words for tile T (L2/L3-hit; consumed
        //     after QK -> latency hidden under the MFMAs)
        u64 mw[2][4];
        #pragma unroll
        for (int g = 0; g < 2; ++g)
            #pragma unroll
            for (int r = 0; r < 4; ++r)
                mw[g][r] = mask[maskRow[g][r] + T];

        // (3) QK from Kbuf[cur]: 16 B-frag reads, each feeds both user groups
        f32x4 S[2][4];
        #pragma unroll
        for (int g = 0; g < 2; ++g)
            #pragma unroll
            for (int nt = 0; nt < 4; ++nt) S[g][nt] = (f32x4){0.f, 0.f, 0.f, 0.f};
        const __bf16* kb = &Kbuf[cur][0];
        #pragma unroll
        for (int nt = 0; nt < 4; ++nt) {
            #pragma unroll
            for (int kk = 0; kk < 4; ++kk) {
                bf16x8 b = *(const bf16x8*)(kb + (nt * 4 + kk) * 512 + lane * 8);
                S[0][nt] = __builtin_amdgcn_mfma_f32_16x16x32_bf16(qf[0][kk], b, S[0][nt], 0, 0, 0);
                S[1][nt] = __builtin_amdgcn_mfma_f32_16x16x32_bf16(qf[1][kk], b, S[1][nt], 0, 0, 0);
            }
        }

        // (4) mask + leaky2 + exp2 -> P quads (items 4n..4n+3 of each row).
        //     bit (4n+nt) of mw[g][r]; pad items have bit 0 -> no edge branch.
        #pragma unroll
        for (int g = 0; g < 2; ++g) {
            #pragma unroll
            for (int r = 0; r < 4; ++r) {
                const unsigned nib = (unsigned)(mw[g][r] >> (4 * n)) & 0xFu;
                bf16x4 pk;
                #pragma unroll
                for (int nt = 0; nt < 4; ++nt) {
                    float s = S[g][nt][r] * SC;
                    s = fminf(s, s + s);            // leaky_relu(slope 2), pre-scaled
                    const bool on = (nib >> nt) & 1u;
                    float p = on ? __builtin_amdgcn_exp2f(s) : 0.f;
                    lacc[g][r] += p;
                    pk[nt] = (__bf16)p;
                }
                *(bf16x4*)(pw + (g * 16 + qd * 4 + r) * 72 + 4 * n) = pk;
            }
        }

        __syncthreads();   // barrier1: drains K(T+1) staging (flew under QK+mask)

        // (6) PV from Vbuf: 16 V B-frag reads, each feeds both groups
        #pragma unroll
        for (int kc = 0; kc < 2; ++kc) {
            bf16x8 af0 = *(const bf16x8*)(pw + (0 * 16 + n) * 72 + kc * 32 + qd * 8);
            bf16x8 af1 = *(const bf16x8*)(pw + (1 * 16 + n) * 72 + kc * 32 + qd * 8);
            #pragma unroll
            for (int dt = 0; dt < 8; ++dt) {
                bf16x8 b = *(const bf16x8*)(&Vbuf[(dt * 2 + kc) * 512 + lane * 8]);
                Oacc[0][dt] = __builtin_amdgcn_mfma_f32_16x16x32_bf16(af0, b, Oacc[0][dt], 0, 0, 0);
                Oacc[1][dt] = __builtin_amdgcn_mfma_f32_16x16x32_bf16(af1, b, Oacc[1][dt], 0, 0, 0);
            }
        }

        __syncthreads();   // barrier2: all waves done PV(T) -> Vbuf reusable

        // (8) issue V(T+1) -> Vbuf (flies under next tile's QK+mask)
        if (more) {
            #pragma unroll
            for (int j = 0; j < 4; ++j) {
                const int c = wave * 4 + j;
                __builtin_amdgcn_global_load_lds((g_u32*)(tbn + (size_t)(16 + c) * 512 + lane * 8),
                                                 (l_u32*)(&Vbuf[c * 512]), 16, 0, 0);
            }
        }
        cur ^= 1;
    }

    // reduce l across the 16 lanes of each quad (lanes jointly cover all items)
    #pragma unroll
    for (int g = 0; g < 2; ++g)
        #pragma unroll
        for (int r = 0; r < 4; ++r) {
            float v = lacc[g][r];
            v += __shfl_xor(v, 1);
            v += __shfl_xor(v, 2);
            v += __shfl_xor(v, 4);
            v += __shfl_xor(v, 8);
            lacc[g][r] = v;
        }
    const size_t cb = (size_t)chunk * QROWS;
    #pragma unroll
    for (int g = 0; g < 2; ++g)
        #pragma unroll
        for (int r = 0; r < 4; ++r) {
            const int user = user0 + g * 16 + qd * 4 + r;
            if (user < N_USERS) {
                #pragma unroll
                for (int dt = 0; dt < 8; ++dt)
                    Opart[(cb + user) * HD + dt * 16 + n] = Oacc[g][dt][r];
                if (n == 0) lpart[cb + user] = lacc[g][r];
            }
        }
}

// ---------------- combine partials: out = (sum_c O_c) / (sum_c l_c) ----------------
__global__ __launch_bounds__(256) void combine_kernel(const float* __restrict__ Opart,
                                                      const float* __restrict__ lpart,
                                                      float* __restrict__ out) {
    const int g = blockIdx.x * 256 + threadIdx.x;   // 323584 threads exactly
    const int base = g * 4;
    const int user = base >> 7;
    const int d = base & 127;
    f32x4 acc = {0.f, 0.f, 0.f, 0.f};
    float l = 0.f;
    #pragma unroll
    for (int c = 0; c < NCHUNK; ++c) {
        acc += *(const f32x4*)(Opart + ((size_t)c * QROWS + user) * HD + d);
        l += lpart[(size_t)c * QROWS + user];
    }
    if (user < N_USERS) {
        f32x4 res = acc / l;
        *(f32x4*)(out + (size_t)user * HD + d) = res;
    }
}

extern "C" void kernel_launch(void* const* d_in, const int* in_sizes, int n_in,
                              void* d_out, int out_size, void* d_ws, size_t ws_size,
                              hipStream_t stream) {
    const float* ufea = (const float*)d_in[0];
    const float* inter = (const float*)d_in[1];
    const int*   adj  = (const int*)d_in[2];
    const float* W    = (const float*)d_in[3];
    const float* bias = (const float*)d_in[4];
    float* out = (float*)d_out;

    char* ws = (char*)d_ws;
    // layout (bytes):
    //   kvg   : 188*32*512*2      =  6,160,384   (tile-chunk-major K/V fragment image)
    //   qg    : 10112*128*2       =  2,588,672
    //   mask  : 10000*188*8       = 15,040,000   (adj bitmask)
    //   Opart : 6*10112*128*4     = 31,064,064
    //   lpart : 6*10112*4         =    242,688   total ~55.1 MB
    __bf16* kvg  = (__bf16*)(ws);
    __bf16* qg   = (__bf16*)(ws + 6160384);
    u64*    mask = (u64*)(ws + 8749056);
    float*  Opart = (float*)(ws + 23789056);
    float*  lpart = (float*)(ws + 54853120);

    prep_kernel<<<dim3(NTILES + QBLOCKS + AMBLOCKS), dim3(256), 0, stream>>>(
        inter, ufea, W, bias, adj, kvg, qg, mask);
    fused_kernel<<<dim3(NCHUNK, UBLOCKS), dim3(256), 0, stream>>>(qg, kvg, mask, Opart, lpart);
    combine_kernel<<<dim3(1264), dim3(256), 0, stream>>>(Opart, lpart, out);
}

// Round 7
// 655.494 us; speedup vs baseline: 1.4282x; 1.1148x over previous
//
#include <hip/hip_runtime.h>
#include <cstdint>
#include <cstddef>

// GAT forward: query = ufea@W^T + b; S = leaky2((q@inter^T)/sqrt(D)) masked by adj;
// out = softmax(S) @ inter.   N=10000 users, M=12000 items, D=128.
// R14: occupancy 2 -> 3 blocks/CU, executed correctly this time.
//   Evidence: fused is latency-bound (R12 counters: MfmaUtil 5.9%, VALU 11%,
//   hbm 25% -- all pipes idle), scheduling fixes null (R8/R11), removing the adj
//   stream null (R13). The untested cure is +50% TLP.
//   - LDS 50 KB (single Kbuf+Vbuf+Pl)  -> 3 blocks = 150 <= 160 KB
//   - native __attribute__((amdgpu_waves_per_eu(3))) (launch_bounds(256,3)
//     mistranslated in R12 -> 84 VGPR + 200MB spill)
//   - group-sequenced QK: S[2][4] -> S[4] (-16 VGPR; K B-frags re-read, LDS has
//     10x headroom) -> natural VGPR demand ~150 under the 170 cap
//   - adj -> two 16-bit masks right after the barrier (av regs die before QK)
//   - NCHUNK 12 -> 9: 711 blocks ~ 2.8/CU matches residency 3
//   prep/combine = R11 structure (adj-mask pass of R13 reverted).

#define N_USERS 10000
#define N_ITEMS 12000
#define HD      128
#define QROWS   10112      // 632*16 padded user rows
#define NCHUNK  9
#define TILE    64
#define NTILES  188        // ceil(12000/64); tile 187 has 32 valid items (zero-padded)
#define UBLOCKS 79         // fused user-blocks of 128
#define QBLOCKS 632        // query blocks of 16 users

typedef __bf16 bf16x8 __attribute__((ext_vector_type(8)));
typedef __bf16 bf16x4 __attribute__((ext_vector_type(4)));
typedef float  f32x4  __attribute__((ext_vector_type(4)));
typedef int    i32x4  __attribute__((ext_vector_type(4)));

typedef const __attribute__((address_space(1))) unsigned int g_u32;
typedef __attribute__((address_space(3))) unsigned int l_u32;

// ---------------- prep: inter -> kvg fragment image  +  query = ufea@W^T + b ----------------
// kvg layout per tile t (32KB): 32 chunks x 512 halves.
//   chunk c<16  (K): c=nt*4+kk, element[lane= qd*16+n][e] = K[t*64 + 4n+nt][kk*32+qd*8+e]
//   chunk 16+cc (V): cc=dt*2+kc, element[lane][e]        = inter[t*64+kc*32+qd*8+e][dt*16+n]
// Invalid items (>=12000) zero-filled -> fused needs no row clamps for K/V.
__global__ __launch_bounds__(256) void prep_kernel(const float* __restrict__ inter,
                                                   const float* __restrict__ ufea,
                                                   const float* __restrict__ W,
                                                   const float* __restrict__ bias,
                                                   __bf16* __restrict__ kvg,
                                                   __bf16* __restrict__ qg) {
    __shared__ __bf16 Tl[128 * 72];   // [d][item_local], pitch 72 (16B-aligned rows)
    const int t = threadIdx.x;
    const int lane = t & 63, wave = t >> 6;
    const int n = lane & 15, qd = lane >> 4;

    if (blockIdx.x < NTILES) {
        // ---- cast path ----
        const int tile = blockIdx.x;
        const int i0 = tile * 64;
        for (int it = 0; it < 8; ++it) {
            int g   = it * 256 + t;
            int row = g >> 5;            // 0..63 item_local
            int d   = (g & 31) * 4;      // 0..124
            int item = i0 + row;
            if (item < N_ITEMS) {
                f32x4 v = *(const f32x4*)(inter + (size_t)item * HD + d);
                Tl[(d + 0) * 72 + row] = (__bf16)v.x;
                Tl[(d + 1) * 72 + row] = (__bf16)v.y;
                Tl[(d + 2) * 72 + row] = (__bf16)v.z;
                Tl[(d + 3) * 72 + row] = (__bf16)v.w;
            } else {
                Tl[(d + 0) * 72 + row] = (__bf16)0.f;
                Tl[(d + 1) * 72 + row] = (__bf16)0.f;
                Tl[(d + 2) * 72 + row] = (__bf16)0.f;
                Tl[(d + 3) * 72 + row] = (__bf16)0.f;
            }
        }
        __syncthreads();
        __bf16* tbase = kvg + (size_t)tile * (32 * 512);
        // K chunks: re-read inter rows from global (L2-hot), cast to bf16
        #pragma unroll
        for (int j = 0; j < 4; ++j) {
            const int c = wave * 4 + j;            // nt = wave, kk = j
            int row = i0 + 4 * n + wave;
            bf16x8 o;
            if (row < N_ITEMS) {
                const float* p = inter + (size_t)row * HD + j * 32 + qd * 8;
                f32x4 lo = *(const f32x4*)p, hi = *(const f32x4*)(p + 4);
                o[0]=(__bf16)lo.x; o[1]=(__bf16)lo.y; o[2]=(__bf16)lo.z; o[3]=(__bf16)lo.w;
                o[4]=(__bf16)hi.x; o[5]=(__bf16)hi.y; o[6]=(__bf16)hi.z; o[7]=(__bf16)hi.w;
            } else {
                #pragma unroll
                for (int e = 0; e < 8; ++e) o[e] = (__bf16)0.f;
            }
            *(bf16x8*)(tbase + (size_t)c * 512 + lane * 8) = o;
        }
        // V chunks: from the LDS transpose
        #pragma unroll
        for (int j = 0; j < 4; ++j) {
            const int cc = wave * 4 + j;           // dt = cc>>1, kc = cc&1
            const int dt = cc >> 1, kc = cc & 1;
            bf16x8 v = *(const bf16x8*)&Tl[(dt * 16 + n) * 72 + kc * 32 + qd * 8];
            *(bf16x8*)(tbase + (size_t)(16 + cc) * 512 + lane * 8) = v;
        }
    } else {
        // ---- query path: 16 users/block; waves split the 8 output nt-tiles ----
        const int user0 = (blockIdx.x - NTILES) * 16;
        int arow = user0 + n; if (arow > N_USERS - 1) arow = N_USERS - 1;

        bf16x8 af[4];
        #pragma unroll
        for (int kk = 0; kk < 4; ++kk) {
            const float* p = ufea + (size_t)arow * HD + kk * 32 + qd * 8;
            f32x4 lo = *(const f32x4*)p, hi = *(const f32x4*)(p + 4);
            bf16x8 a;
            a[0]=(__bf16)lo.x; a[1]=(__bf16)lo.y; a[2]=(__bf16)lo.z; a[3]=(__bf16)lo.w;
            a[4]=(__bf16)hi.x; a[5]=(__bf16)hi.y; a[6]=(__bf16)hi.z; a[7]=(__bf16)hi.w;
            af[kk] = a;
        }
        #pragma unroll
        for (int h = 0; h < 2; ++h) {
            const int nt = wave * 2 + h;
            f32x4 acc = {0.f, 0.f, 0.f, 0.f};
            #pragma unroll
            for (int kk = 0; kk < 4; ++kk) {
                const float* p = W + (size_t)(nt * 16 + n) * HD + kk * 32 + qd * 8;
                f32x4 lo = *(const f32x4*)p, hi = *(const f32x4*)(p + 4);
                bf16x8 b;
                b[0]=(__bf16)lo.x; b[1]=(__bf16)lo.y; b[2]=(__bf16)lo.z; b[3]=(__bf16)lo.w;
                b[4]=(__bf16)hi.x; b[5]=(__bf16)hi.y; b[6]=(__bf16)hi.z; b[7]=(__bf16)hi.w;
                acc = __builtin_amdgcn_mfma_f32_16x16x32_bf16(af[kk], b, acc, 0, 0, 0);
            }
            const float bv = bias[nt * 16 + n];
            #pragma unroll
            for (int r = 0; r < 4; ++r) {
                int row = user0 + qd * 4 + r;      // < QROWS always
                qg[(size_t)row * HD + nt * 16 + n] = (__bf16)(acc[r] + bv);
            }
        }
    }
}

// ---------------- fused: S = q@k^T, mask+leaky+exp, O += P@V, l += rowsum ----------------
// Target 3 blocks/CU (12 waves). Per tile: raw barrier A -> stage K/V + load adj
// -> __syncthreads -> compact adj to 2x16-bit masks -> QK+mask per group
// (sequenced, S[4] live) -> PV both groups.
__global__ __launch_bounds__(256)
__attribute__((amdgpu_waves_per_eu(3)))
void fused_kernel(const __bf16* __restrict__ qg,
                  const __bf16* __restrict__ kvg,
                  const int* __restrict__ adj,
                  float* __restrict__ Opart,
                  float* __restrict__ lpart) {
    __shared__ __bf16 Kbuf[16 * 512];     // chunk c=(nt*4+kk): K[j0+4n+nt][kk*32+qd*8..]
    __shared__ __bf16 Vbuf[16 * 512];     // chunk c=(dt*2+kc): V_T[dt*16+n][j0+kc*32+qd*8..]
    __shared__ __bf16 Pl[4][32 * 72];     // per-wave P: [user 0..31][item 0..63], pitch 72
    const int lane = threadIdx.x & 63, wave = threadIdx.x >> 6;
    const int n = lane & 15, qd = lane >> 4;
    const int user0 = blockIdx.y * 128 + wave * 32;   // wave covers users user0..user0+31
    const int chunk = blockIdx.x;
    const int t0 = (chunk * NTILES) / NCHUNK;
    const int t1 = ((chunk + 1) * NTILES) / NCHUNK;
    const float SC = (float)(1.4426950408889634 * 0.08838834764831845); // log2(e)/sqrt(128)

    bf16x8 qf[2][4];
    #pragma unroll
    for (int g = 0; g < 2; ++g)
        #pragma unroll
        for (int kk = 0; kk < 4; ++kk)
            qf[g][kk] = *(const bf16x8*)(qg + (size_t)(user0 + g * 16 + n) * HD + kk * 32 + qd * 8);

    f32x4 Oacc[2][8];
    #pragma unroll
    for (int g = 0; g < 2; ++g)
        #pragma unroll
        for (int dt = 0; dt < 8; ++dt) Oacc[g][dt] = (f32x4){0.f, 0.f, 0.f, 0.f};
    float lacc[2][4] = {{0.f,0.f,0.f,0.f},{0.f,0.f,0.f,0.f}};

    int adjOff[2][4];   // element offsets (10000*12000 < 2^31)
    #pragma unroll
    for (int g = 0; g < 2; ++g)
        #pragma unroll
        for (int r = 0; r < 4; ++r) {
            int u = user0 + g * 16 + qd * 4 + r;
            if (u > N_USERS - 1) u = N_USERS - 1;
            adjOff[g][r] = u * N_ITEMS;
        }
    __bf16* pw = &Pl[wave][0];

    for (int T = t0; T < t1; ++T) {
        const int j0 = T * TILE;
        const __bf16* tb = kvg + (size_t)T * (32 * 512);

        // barrier A: all waves finished reading Kbuf/Vbuf of tile T-1 (their
        // ds_reads were consumed by MFMAs -> already retired; raw barrier ok)
        __builtin_amdgcn_s_barrier();

        // stage K(T)+V(T): 8 contiguous 1KB bursts per wave
        #pragma unroll
        for (int j = 0; j < 4; ++j) {
            const int c = wave * 4 + j;
            __builtin_amdgcn_global_load_lds((g_u32*)(tb + (size_t)c * 512 + lane * 8),
                                             (l_u32*)(&Kbuf[c * 512]), 16, 0, 0);
        }
        #pragma unroll
        for (int j = 0; j < 4; ++j) {
            const int c = wave * 4 + j;
            __builtin_amdgcn_global_load_lds((g_u32*)(tb + (size_t)(16 + c) * 512 + lane * 8),
                                             (l_u32*)(&Vbuf[c * 512]), 16, 0, 0);
        }
        // adj(T): one i32x4 per (group,row) covering items j0+4n..4n+3
        i32x4 av[2][4];
        {
            int col4 = j0 + 4 * n;
            if (col4 > N_ITEMS - 4) col4 = N_ITEMS - 4;
            #pragma unroll
            for (int g = 0; g < 2; ++g)
                #pragma unroll
                for (int r = 0; r < 4; ++r)
                    av[g][r] = __builtin_nontemporal_load((const i32x4*)(adj + adjOff[g][r] + col4));
        }
        __syncthreads();   // barrier B: drains staging + adj (12 waves/CU cover)

        // compact adj to two 16-bit masks; av regs die here, before QK.
        // bit (r*4+nt) = edge for item j0+4n+nt, user row qd*4+r of group g.
        unsigned m0 = 0, m1 = 0;
        #pragma unroll
        for (int r = 0; r < 4; ++r)
            #pragma unroll
            for (int nt = 0; nt < 4; ++nt) {
                m0 |= (unsigned)(av[0][r][nt] > 0) << (r * 4 + nt);
                m1 |= (unsigned)(av[1][r][nt] > 0) << (r * 4 + nt);
            }
        // pad-item validity (only tile 187 has invalid cols): nibble replicated
        unsigned vnib = 0;
        #pragma unroll
        for (int nt = 0; nt < 4; ++nt)
            vnib |= (unsigned)(j0 + 4 * n + nt < N_ITEMS) << nt;
        const unsigned vrep = vnib * 0x1111u;
        m0 &= vrep; m1 &= vrep;

        // QK + mask + exp, one user group at a time (S[4] live -> -16 VGPR)
        #pragma unroll
        for (int g = 0; g < 2; ++g) {
            f32x4 S[4];
            #pragma unroll
            for (int nt = 0; nt < 4; ++nt) S[nt] = (f32x4){0.f, 0.f, 0.f, 0.f};
            #pragma unroll
            for (int nt = 0; nt < 4; ++nt) {
                #pragma unroll
                for (int kk = 0; kk < 4; ++kk) {
                    bf16x8 b = *(const bf16x8*)(&Kbuf[(nt * 4 + kk) * 512 + lane * 8]);
                    S[nt] = __builtin_amdgcn_mfma_f32_16x16x32_bf16(qf[g][kk], b, S[nt], 0, 0, 0);
                }
            }
            const unsigned mg = g ? m1 : m0;
            #pragma unroll
            for (int r = 0; r < 4; ++r) {
                bf16x4 pk;
                #pragma unroll
                for (int nt = 0; nt < 4; ++nt) {
                    float s = S[nt][r] * SC;
                    s = fminf(s, s + s);            // leaky_relu(slope 2), pre-scaled
                    const bool on = (mg >> (r * 4 + nt)) & 1u;
                    float p = on ? __builtin_amdgcn_exp2f(s) : 0.f;
                    lacc[g][r] += p;
                    pk[nt] = (__bf16)p;
                }
                *(bf16x4*)(pw + (g * 16 + qd * 4 + r) * 72 + 4 * n) = pk;
            }
        }

        // PV: 16 V B-frag reads, each feeding both groups (32 MFMAs)
        #pragma unroll
        for (int kc = 0; kc < 2; ++kc) {
            bf16x8 af0 = *(const bf16x8*)(pw + (0 * 16 + n) * 72 + kc * 32 + qd * 8);
            bf16x8 af1 = *(const bf16x8*)(pw + (1 * 16 + n) * 72 + kc * 32 + qd * 8);
            #pragma unroll
            for (int dt = 0; dt < 8; ++dt) {
                bf16x8 b = *(const bf16x8*)(&Vbuf[(dt * 2 + kc) * 512 + lane * 8]);
                Oacc[0][dt] = __builtin_amdgcn_mfma_f32_16x16x32_bf16(af0, b, Oacc[0][dt], 0, 0, 0);
                Oacc[1][dt] = __builtin_amdgcn_mfma_f32_16x16x32_bf16(af1, b, Oacc[1][dt], 0, 0, 0);
            }
        }
    }

    // reduce l across the 16 lanes of each quad (lanes jointly cover all items)
    #pragma unroll
    for (int g = 0; g < 2; ++g)
        #pragma unroll
        for (int r = 0; r < 4; ++r) {
            float v = lacc[g][r];
            v += __shfl_xor(v, 1);
            v += __shfl_xor(v, 2);
            v += __shfl_xor(v, 4);
            v += __shfl_xor(v, 8);
            lacc[g][r] = v;
        }
    const size_t cb = (size_t)chunk * QROWS;
    #pragma unroll
    for (int g = 0; g < 2; ++g)
        #pragma unroll
        for (int r = 0; r < 4; ++r) {
            const int user = user0 + g * 16 + qd * 4 + r;
            if (user < N_USERS) {
                #pragma unroll
                for (int dt = 0; dt < 8; ++dt)
                    Opart[(cb + user) * HD + dt * 16 + n] = Oacc[g][dt][r];
                if (n == 0) lpart[cb + user] = lacc[g][r];
            }
        }
}

// ---------------- combine partials: out = (sum_c O_c) / (sum_c l_c) ----------------
__global__ __launch_bounds__(256) void combine_kernel(const float* __restrict__ Opart,
                                                      const float* __restrict__ lpart,
                                                      float* __restrict__ out) {
    const int g = blockIdx.x * 256 + threadIdx.x;   // 323584 threads exactly
    const int base = g * 4;
    const int user = base >> 7;
    const int d = base & 127;
    f32x4 acc = {0.f, 0.f, 0.f, 0.f};
    float l = 0.f;
    #pragma unroll
    for (int c = 0; c < NCHUNK; ++c) {
        acc += *(const f32x4*)(Opart + ((size_t)c * QROWS + user) * HD + d);
        l += lpart[(size_t)c * QROWS + user];
    }
    if (user < N_USERS) {
        f32x4 res = acc / l;
        *(f32x4*)(out + (size_t)user * HD + d) = res;
    }
}

extern "C" void kernel_launch(void* const* d_in, const int* in_sizes, int n_in,
                              void* d_out, int out_size, void* d_ws, size_t ws_size,
                              hipStream_t stream) {
    const float* ufea = (const float*)d_in[0];
    const float* inter = (const float*)d_in[1];
    const int*   adj  = (const int*)d_in[2];
    const float* W    = (const float*)d_in[3];
    const float* bias = (const float*)d_in[4];
    float* out = (float*)d_out;

    char* ws = (char*)d_ws;
    // layout (bytes):
    //   kvg   : 188*32*512*2      =  6,160,384   (tile-chunk-major K/V fragment image)
    //   qg    : 10112*128*2       =  2,588,672
    //   Opart : 9*10112*128*4     = 46,596,096
    //   lpart : 9*10112*4         =    364,032   total ~55.7 MB
    __bf16* kvg  = (__bf16*)(ws);
    __bf16* qg   = (__bf16*)(ws + 6160384);
    float*  Opart = (float*)(ws + 8749056);
    float*  lpart = (float*)(ws + 55345152);

    prep_kernel<<<dim3(NTILES + QBLOCKS), dim3(256), 0, stream>>>(inter, ufea, W, bias, kvg, qg);
    fused_kernel<<<dim3(NCHUNK, UBLOCKS), dim3(256), 0, stream>>>(qg, kvg, adj, Opart, lpart);
    combine_kernel<<<dim3(1264), dim3(256), 0, stream>>>(Opart, lpart, out);
}